// Round 1
// baseline (186.255 us; speedup 1.0000x reference)
//
#include <hip/hip_runtime.h>
#include <math.h>

// N=8192 rows, D=4096 cols, fp32.
// out[row] = -0.5*(df + D) * log(1 + sum_d (X[row,d]-mean[d])^2 / df)
//
// Memory-bound: 128 MiB read of X dominates. One block per row; each of 256
// threads loads 4 float4 (coalesced 16B/lane), wave64 shuffle reduce, LDS
// cross-wave combine, lane 0 epilogue.

#define ROWS 8192
#define COLS 4096

__global__ __launch_bounds__(256) void
row_logden_kernel(const float* __restrict__ X,
                  const float* __restrict__ mean,
                  const float* __restrict__ df,
                  float* __restrict__ out) {
    const int row = blockIdx.x;
    const int t = threadIdx.x;

    const float4* __restrict__ xr =
        reinterpret_cast<const float4*>(X + (size_t)row * COLS);
    const float4* __restrict__ mr =
        reinterpret_cast<const float4*>(mean);

    float acc = 0.0f;
    // COLS/4 = 1024 float4 per row; 256 threads -> 4 iterations.
#pragma unroll
    for (int k = 0; k < 4; ++k) {
        const int i = t + k * 256;
        const float4 x = xr[i];
        const float4 m = mr[i];
        const float dx = x.x - m.x;
        const float dy = x.y - m.y;
        const float dz = x.z - m.z;
        const float dw = x.w - m.w;
        acc += dx * dx + dy * dy + dz * dz + dw * dw;
    }

    // Wave64 butterfly/shuffle-down reduction.
#pragma unroll
    for (int off = 32; off > 0; off >>= 1)
        acc += __shfl_down(acc, off, 64);

    __shared__ float partial[4];
    const int wave = t >> 6;
    const int lane = t & 63;
    if (lane == 0) partial[wave] = acc;
    __syncthreads();

    if (t == 0) {
        const float s = partial[0] + partial[1] + partial[2] + partial[3];
        const float dfv = df[0];
        out[row] = -0.5f * (dfv + (float)COLS) * logf(1.0f + s / dfv);
    }
}

extern "C" void kernel_launch(void* const* d_in, const int* in_sizes, int n_in,
                              void* d_out, int out_size, void* d_ws, size_t ws_size,
                              hipStream_t stream) {
    const float* X    = (const float*)d_in[0];
    const float* mean = (const float*)d_in[1];
    const float* df   = (const float*)d_in[2];
    float* out = (float*)d_out;

    row_logden_kernel<<<ROWS, 256, 0, stream>>>(X, mean, df, out);
}

// Round 3
// 178.950 us; speedup vs baseline: 1.0408x; 1.0408x over previous
//
#include <hip/hip_runtime.h>
#include <math.h>

// N=8192 rows, D=4096 cols, fp32.
// out[row] = -0.5*(df + D) * log(1 + sum_d (X[row,d]-mean[d])^2 / df)
//
// Memory-bound: 128 MiB streaming read of X. One WAVE per row:
//  - 16 float4 loads/lane (16-deep memory pipeline, 16 KB/row per wave)
//  - nontemporal on X (streamed once; keep L2 for mean)
//  - wave64 shuffle reduction only — no __syncthreads, no LDS
// grid = 2048 blocks x 4 waves = 8192 rows.
//
// NOTE: __builtin_nontemporal_load needs a native clang vector type, not
// HIP_vector_type<float,4> — use ext_vector_type(4) float.

#define ROWS 8192
#define COLS 4096

typedef float f32x4 __attribute__((ext_vector_type(4)));

__global__ __launch_bounds__(256, 4) void
row_logden_kernel(const float* __restrict__ X,
                  const float* __restrict__ mean,
                  const float* __restrict__ df,
                  float* __restrict__ out) {
    const int wave = threadIdx.x >> 6;
    const int lane = threadIdx.x & 63;
    const int row  = blockIdx.x * 4 + wave;

    const f32x4* __restrict__ xr =
        reinterpret_cast<const f32x4*>(X + (size_t)row * COLS);
    const f32x4* __restrict__ mr =
        reinterpret_cast<const f32x4*>(mean);

    // COLS/4 = 1024 float4 per row; 64 lanes -> 16 float4 per lane.
    float acc = 0.0f;
#pragma unroll
    for (int k = 0; k < 16; ++k) {
        const int i = lane + k * 64;
        const f32x4 x = __builtin_nontemporal_load(&xr[i]);
        const f32x4 m = mr[i];
        const f32x4 d = x - m;
        acc += d.x * d.x + d.y * d.y + d.z * d.z + d.w * d.w;
    }

    // Wave64 shuffle-down reduction.
#pragma unroll
    for (int off = 32; off > 0; off >>= 1)
        acc += __shfl_down(acc, off, 64);

    if (lane == 0) {
        const float dfv = df[0];
        out[row] = -0.5f * (dfv + (float)COLS) * logf(1.0f + acc / dfv);
    }
}

extern "C" void kernel_launch(void* const* d_in, const int* in_sizes, int n_in,
                              void* d_out, int out_size, void* d_ws, size_t ws_size,
                              hipStream_t stream) {
    const float* X    = (const float*)d_in[0];
    const float* mean = (const float*)d_in[1];
    const float* df   = (const float*)d_in[2];
    float* out = (float*)d_out;

    row_logden_kernel<<<ROWS / 4, 256, 0, stream>>>(X, mean, df, out);
}